// Round 2
// baseline (678.661 us; speedup 1.0000x reference)
//
#include <hip/hip_runtime.h>
#include <math.h>

#define NATOM 100000
#define MNBR 12
#define FDIM 128
#define NFDIM 64

typedef __attribute__((ext_vector_type(8))) short bf16x8;
typedef __attribute__((ext_vector_type(4))) float f32x4;
typedef unsigned short u16;

__device__ inline u16 f2bf(float x) {
    union { float f; unsigned u; } v; v.f = x;
    unsigned r = v.u + 0x7FFFu + ((v.u >> 16) & 1u);   // RNE
    return (u16)(r >> 16);
}

__device__ inline float b2f(u16 u) {
    union { unsigned u; float f; } v; v.u = ((unsigned)u) << 16;
    return v.f;
}

__device__ inline void st4bf(short* p, float4 x) {
    unsigned lo = (unsigned)f2bf(x.x) | ((unsigned)f2bf(x.y) << 16);
    unsigned hi = (unsigned)f2bf(x.z) | ((unsigned)f2bf(x.w) << 16);
    *(uint2*)p = make_uint2(lo, hi);
}

// ---------------------------------------------------------------------------
// K0: pack Wq|Wk|Wv -> pk1, Wn -> pk2, Wo -> pk3 in bf16 B-fragment order.
// ---------------------------------------------------------------------------
__global__ __launch_bounds__(256) void pack_weights(
    const float* __restrict__ Wq, const float* __restrict__ Wk,
    const float* __restrict__ Wv, const float* __restrict__ Wn,
    const float* __restrict__ Wo,
    short* __restrict__ pk1, short* __restrict__ pk2, short* __restrict__ pk3)
{
    int g = blockIdx.x * 256 + threadIdx.x;
    if (g < 49152) {                       // Wq|Wk|Wv: 24 frags x 4 ksteps
        int fe = g >> 9;
        int r = g & 511;
        int lane = r >> 3, jj = r & 7;
        int s = fe & 3, f = fe >> 2;
        int ct = f & 7, mt = f >> 3;
        int k = s * 32 + (lane >> 4) * 8 + jj;
        int n = ct * 16 + (lane & 15);
        const float* W = (mt == 0) ? Wq : ((mt == 1) ? Wk : Wv);
        pk1[g] = (short)f2bf(W[k * 128 + n]);
    } else if (g < 57344) {                // Wn: 8 frags x 2 ksteps
        int g2 = g - 49152;
        int fe = g2 >> 9;
        int r = g2 & 511;
        int lane = r >> 3, jj = r & 7;
        int s = fe & 1, ct = fe >> 1;
        int k = s * 32 + (lane >> 4) * 8 + jj;
        int n = ct * 16 + (lane & 15);
        pk2[g2] = (short)f2bf(Wn[k * 128 + n]);
    } else {                               // Wo: 8 frags x 4 ksteps
        int g3 = g - 57344;
        int fe = g3 >> 9;
        int r = g3 & 511;
        int lane = r >> 3, jj = r & 7;
        int s = fe & 3, ct = fe >> 2;
        int k = s * 32 + (lane >> 4) * 8 + jj;
        int n = ct * 16 + (lane & 15);
        pk3[g3] = (short)f2bf(Wo[k * 128 + n]);
    }
}

// ---------------------------------------------------------------------------
// K1: QKV via MFMA (unchanged from r1). Outputs bf16.
// ---------------------------------------------------------------------------
__global__ __launch_bounds__(256) void qkv_mfma(
    const float* __restrict__ atom_fea,
    const short* __restrict__ pk1,
    const float* __restrict__ bq, const float* __restrict__ bk,
    const float* __restrict__ bv,
    u16* __restrict__ q, u16* __restrict__ k, u16* __restrict__ v)
{
    __shared__ short s_a[128 * 136];   // 34816 B
    const int tid = threadIdx.x;
    const int base = blockIdx.x * 128;
#pragma unroll
    for (int e = 0; e < 16; ++e) {
        int f4 = e * 256 + tid;
        int row = f4 >> 5, c4 = f4 & 31;
        int atom = base + row;
        float4 x = make_float4(0.f, 0.f, 0.f, 0.f);
        if (atom < NATOM) x = *(const float4*)(atom_fea + (size_t)atom * 128 + c4 * 4);
        st4bf(&s_a[row * 136 + c4 * 4], x);
    }
    __syncthreads();

    const int lane = tid & 63, w = tid >> 6;
    const int quad = lane >> 4, j16 = lane & 15;

    for (int rt = 0; rt < 8; ++rt) {
        f32x4 acc[6];
#pragma unroll
        for (int fl = 0; fl < 6; ++fl) acc[fl] = (f32x4){0.f, 0.f, 0.f, 0.f};

        const short* arow = &s_a[(rt * 16 + j16) * 136];
#pragma unroll
        for (int s = 0; s < 4; ++s) {
            bf16x8 af = *(const bf16x8*)(arow + s * 32 + quad * 8);
            bf16x8 bfr[6];
#pragma unroll
            for (int fl = 0; fl < 6; ++fl)
                bfr[fl] = *(const bf16x8*)(pk1 + ((((w * 6 + fl) * 4 + s) * 64 + lane) << 3));
#pragma unroll
            for (int fl = 0; fl < 6; ++fl)
                acc[fl] = __builtin_amdgcn_mfma_f32_16x16x32_bf16(af, bfr[fl], acc[fl], 0, 0, 0);
        }
#pragma unroll
        for (int fl = 0; fl < 6; ++fl) {
            const int f = w * 6 + fl;
            const int mt = f >> 3, ct = f & 7;
            const int col = ct * 16 + j16;
            const float b = (mt == 0 ? bq : (mt == 1 ? bk : bv))[col];
            u16* op = (mt == 0 ? q : (mt == 1 ? k : v));
#pragma unroll
            for (int r = 0; r < 4; ++r) {
                int atom = base + rt * 16 + quad * 4 + r;
                if (atom < NATOM) op[(unsigned)atom * 128u + col] = f2bf(acc[fl][r] + b);
            }
        }
    }
}

// ---------------------------------------------------------------------------
// K2: fused neighbor projection (MFMA) + gather + attention.
// NEW: k/v rows for the current atom are gathered into LDS by a single
// designated wave using 6x global_load_lds dwordx4 (64 lanes x 16B, per-lane
// global addr, linear LDS dest). Score/softmax reads k/v from LDS.
// LDS kv layout: 6 groups of 4 rows; group stride 1056 B (1024 + 32 pad)
// so quad rows land on shifted banks. rows 0..11 = k[m], 12..23 = v[m].
// ---------------------------------------------------------------------------
__global__ __launch_bounds__(256) void attn_mfma(
    const float* __restrict__ nbr_fea,
    const int*   __restrict__ nbr_idx,
    const short* __restrict__ pk2,
    const float* __restrict__ bn,
    u16* qatt,
    const u16* __restrict__ kbuf,
    const u16* __restrict__ vbuf)
{
    __shared__ __align__(16) short s_a[8 * 16 * 72];   // 18432 B
    __shared__ __align__(16) u16   s_q[8 * 128];       //  2048 B
    __shared__ __align__(16) u16   s_kv[6 * 528];      //  6336 B (incl. pads)
    const int tid = threadIdx.x;
    const long long blk = blockIdx.x;

    const float* gsrc = nbr_fea + blk * 6144;
#pragma unroll
    for (int e = 0; e < 6; ++e) {
        int f4 = e * 256 + tid;            // [0,1536): 96 rows x 16 float4
        int r = f4 >> 4, c4 = f4 & 15;
        int a = r / 12, m = r - a * 12;
        int lrow = (m / 3) * 4 + (m % 3);  // balanced pad layout
        float4 x = *(const float4*)(gsrc + (size_t)f4 * 4);
        st4bf(&s_a[(a * 16 + lrow) * 72 + c4 * 4], x);
    }
    {   // zero pad rows r=3 of each quad
        int prow = tid >> 3, c = tid & 7;
        int a = prow >> 2, qd = prow & 3;
        *(uint4*)&s_a[(a * 16 + qd * 4 + 3) * 72 + c * 8] = make_uint4(0, 0, 0, 0);
    }
    if (tid < 128) {                       // stage q rows for this block
        ((uint4*)s_q)[tid] = ((const uint4*)(qatt + (size_t)blk * 1024))[tid];
    }

    const int lane = tid & 63, w = tid >> 6;
    const int quad = lane >> 4, j16 = lane & 15;
    const unsigned base8 = (unsigned)blk * 8u;

    // Preload neighbor indices for the two atoms this wave gathers (a=w, w+4).
    // Gather inst j covers kv-rows 4j..4j+3; this lane's row-in-group = quad,
    // so its neighbor m = 4*(j%3) + quad, v-section iff j>=3.
    int nid[2][3];
#pragma unroll
    for (int s = 0; s < 2; ++s)
#pragma unroll
        for (int r = 0; r < 3; ++r)
            nid[s][r] = nbr_idx[(base8 + w + 4 * s) * 12u + r * 4 + quad];

    __syncthreads();

    bf16x8 bfr[2][2];                      // [hh][kstep]
#pragma unroll
    for (int hh = 0; hh < 2; ++hh)
#pragma unroll
        for (int s = 0; s < 2; ++s) {
            int ct = w * 2 + hh;
            bfr[hh][s] = *(const bf16x8*)(pk2 + (((ct * 2 + s) * 64 + lane) << 3));
        }

    const float bnc0 = bn[w * 32 + j16];
    const float bnc1 = bn[w * 32 + 16 + j16];
    const int cb = w * 32 + j16;
    const int lchunk = (lane & 15) << 3;   // u16 offset of this lane's 16B chunk

    // issue the 6 row-group gathers for atom a (called only by wave a&3)
    auto issue = [&](int a, int s) {
#pragma unroll
        for (int j = 0; j < 6; ++j) {
            const int r = (j >= 3) ? (j - 3) : j;
            const u16* src = ((j >= 3) ? vbuf : kbuf)
                + (((size_t)(unsigned)nid[s][r]) << 7) + lchunk;
            __builtin_amdgcn_global_load_lds(
                (const __attribute__((address_space(1))) void*)src,
                (__attribute__((address_space(3))) void*)((char*)s_kv + j * 1056),
                16, 0, 0);
        }
    };
    if (w == 0) issue(0, 0);

#pragma unroll
    for (int a = 0; a < 8; ++a) {
        const unsigned n = base8 + a;

        // neighbor projection MFMA (overlaps gather flight)
        f32x4 acc0 = (f32x4){0.f, 0.f, 0.f, 0.f};
        f32x4 acc1 = (f32x4){0.f, 0.f, 0.f, 0.f};
#pragma unroll
        for (int s = 0; s < 2; ++s) {
            bf16x8 af = *(const bf16x8*)&s_a[(a * 16 + j16) * 72 + s * 32 + quad * 8];
            acc0 = __builtin_amdgcn_mfma_f32_16x16x32_bf16(af, bfr[0][s], acc0, 0, 0, 0);
            acc1 = __builtin_amdgcn_mfma_f32_16x16x32_bf16(af, bfr[1][s], acc1, 0, 0, 0);
        }

        __syncthreads();   // #1: drains vmcnt -> all 24 kv rows for atom a in LDS

#pragma unroll
        for (int hh = 0; hh < 2; ++hh) {
            const int c = cb + hh * 16;
            const float qv = b2f(s_q[a * 128 + c]);
            const float bnc = hh ? bnc1 : bnc0;
            const f32x4 t = hh ? acc1 : acc0;
            float sc[3], nv[3];
#pragma unroll
            for (int r = 0; r < 3; ++r) {
                const int m = quad * 3 + r;            // this quad's neighbor
                const int mk = m, mv = m + 12;
                float kkv = b2f(s_kv[(mk >> 2) * 528 + (mk & 3) * 128 + c]);
                float vvv = b2f(s_kv[(mv >> 2) * 528 + (mv & 3) * 128 + c]);
                float tm = t[r] + bnc;                 // nbr_t + bn
                float nk = kkv + tm;
                nv[r] = vvv + tm;
                float p = qv * nk;
                p += __shfl_xor(p, 1, 16);
                p += __shfl_xor(p, 2, 16);
                p += __shfl_xor(p, 4, 16);
                p += __shfl_xor(p, 8, 16);
                sc[r] = p * 0.25f;                     // 1/sqrt(16)
            }
            float mx = fmaxf(fmaxf(sc[0], sc[1]), sc[2]);
            mx = fmaxf(mx, __shfl_xor(mx, 16));
            mx = fmaxf(mx, __shfl_xor(mx, 32));
            float es = 0.f, av = 0.f;
#pragma unroll
            for (int r = 0; r < 3; ++r) {
                float e = __expf(sc[r] - mx);
                es += e;
                av += e * nv[r];
            }
            es += __shfl_xor(es, 16); es += __shfl_xor(es, 32);
            av += __shfl_xor(av, 16); av += __shfl_xor(av, 32);
            if (quad == 0) qatt[n * 128u + c] = f2bf(av * __builtin_amdgcn_rcpf(es));
        }

        __syncthreads();   // #2: everyone done reading s_kv; safe to refill
        if (a < 7 && w == ((a + 1) & 3)) issue(a + 1, (a + 1) >> 2);
    }
}

// ---------------------------------------------------------------------------
// K3: out projection (MFMA) + sigmoid gate + residual + LayerNorm (unchanged).
// ---------------------------------------------------------------------------
__global__ __launch_bounds__(256) void out_mfma(
    const u16* __restrict__ attb, const float* __restrict__ atom_fea,
    const short* __restrict__ pk3, const float* __restrict__ bo,
    const float* __restrict__ Wg, const float* __restrict__ bg,
    const float* __restrict__ gamma, const float* __restrict__ beta,
    float* __restrict__ out)
{
    __shared__ short s_a[64 * 136];    // 17408 B (att tile, bf16)
    __shared__ float s_o[64 * 132];    // 33792 B (out tile, fp32)
    const int tid = threadIdx.x;
    const int base = blockIdx.x * 64;
#pragma unroll
    for (int e = 0; e < 4; ++e) {
        int u = e * 256 + tid;             // 64 rows x 16 uint4
        int row = u >> 4, c8 = u & 15;
        int atom = base + row;
        uint4 x = make_uint4(0, 0, 0, 0);
        if (atom < NATOM) x = *(const uint4*)(attb + (size_t)atom * 128 + c8 * 8);
        *(uint4*)&s_a[row * 136 + c8 * 8] = x;
    }
    __syncthreads();

    const int lane = tid & 63, w = tid >> 6;
    const int quad = lane >> 4, j16 = lane & 15;

    f32x4 acc[8];
#pragma unroll
    for (int f = 0; f < 8; ++f) acc[f] = (f32x4){0.f, 0.f, 0.f, 0.f};

    const short* arow = &s_a[(w * 16 + j16) * 136];
#pragma unroll
    for (int s = 0; s < 4; ++s) {
        bf16x8 af = *(const bf16x8*)(arow + s * 32 + quad * 8);
        bf16x8 bfr[8];
#pragma unroll
        for (int f = 0; f < 8; ++f)
            bfr[f] = *(const bf16x8*)(pk3 + (((f * 4 + s) * 64 + lane) << 3));
#pragma unroll
        for (int f = 0; f < 8; ++f)
            acc[f] = __builtin_amdgcn_mfma_f32_16x16x32_bf16(af, bfr[f], acc[f], 0, 0, 0);
    }
#pragma unroll
    for (int f = 0; f < 8; ++f) {
        const int col = f * 16 + j16;
        const float b = bo[col];
#pragma unroll
        for (int r = 0; r < 4; ++r)
            s_o[(w * 16 + quad * 4 + r) * 132 + col] = acc[f][r] + b;
    }
    __syncthreads();

    const int g = tid >> 4;
    const int r16 = tid & 15;
    for (int p = 0; p < 4; ++p) {
        const int a_loc = p * 16 + g;
        const int atom = base + a_loc;
        const bool ok = (atom < NATOM);
        float o8[8], res8[8];
        float pg = 0.f;
#pragma unroll
        for (int tt = 0; tt < 8; ++tt) {
            int jj = r16 + tt * 16;
            o8[tt] = s_o[a_loc * 132 + jj];
            res8[tt] = ok ? atom_fea[(size_t)atom * 128 + jj] : 0.f;
            pg += o8[tt] * Wg[jj] + res8[tt] * Wg[128 + jj];
        }
        pg += __shfl_xor(pg, 1, 16);
        pg += __shfl_xor(pg, 2, 16);
        pg += __shfl_xor(pg, 4, 16);
        pg += __shfl_xor(pg, 8, 16);
        const float gt = 1.f / (1.f + __expf(-(pg + bg[0])));

        float s1 = 0.f, s2 = 0.f;
        float gv8[8];
#pragma unroll
        for (int tt = 0; tt < 8; ++tt) {
            float gv = gt * o8[tt] + (1.f - gt) * res8[tt];
            gv8[tt] = gv;
            s1 += gv; s2 += gv * gv;
        }
        s1 += __shfl_xor(s1, 1, 16); s2 += __shfl_xor(s2, 1, 16);
        s1 += __shfl_xor(s1, 2, 16); s2 += __shfl_xor(s2, 2, 16);
        s1 += __shfl_xor(s1, 4, 16); s2 += __shfl_xor(s2, 4, 16);
        s1 += __shfl_xor(s1, 8, 16); s2 += __shfl_xor(s2, 8, 16);
        const float mu = s1 * (1.f / 128.f);
        const float var = s2 * (1.f / 128.f) - mu * mu;
        const float rs = rsqrtf(var + 1e-5f);
        if (ok) {
#pragma unroll
            for (int tt = 0; tt < 8; ++tt) {
                int jj = r16 + tt * 16;
                out[(size_t)atom * 128 + jj] =
                    (gv8[tt] - mu) * rs * gamma[jj] + beta[jj];
            }
        }
    }
}

// ---------------------------------------------------------------------------
extern "C" void kernel_launch(void* const* d_in, const int* in_sizes, int n_in,
                              void* d_out, int out_size, void* d_ws, size_t ws_size,
                              hipStream_t stream) {
    const float* atom_fea = (const float*)d_in[0];
    const float* nbr_fea  = (const float*)d_in[1];
    const int*   nbr_idx  = (const int*)d_in[2];
    const float* Wq = (const float*)d_in[3];
    const float* bq = (const float*)d_in[4];
    const float* Wk = (const float*)d_in[5];
    const float* bk = (const float*)d_in[6];
    const float* Wv = (const float*)d_in[7];
    const float* bv = (const float*)d_in[8];
    const float* Wn = (const float*)d_in[9];
    const float* bn = (const float*)d_in[10];
    const float* Wo = (const float*)d_in[11];
    const float* bo = (const float*)d_in[12];
    const float* Wg = (const float*)d_in[13];
    const float* bg = (const float*)d_in[14];
    const float* gm = (const float*)d_in[15];
    const float* bt = (const float*)d_in[16];

    u16* qbuf = (u16*)d_ws;                           // [N,128] bf16 -> att
    u16* kbuf = qbuf + (size_t)NATOM * FDIM;
    u16* vbuf = kbuf + (size_t)NATOM * FDIM;
    short* pk1 = (short*)(vbuf + (size_t)NATOM * FDIM);   // 49152 bf16
    short* pk2 = pk1 + 49152;                             // 8192 bf16
    short* pk3 = pk2 + 8192;                              // 16384 bf16
    float* outp = (float*)d_out;

    pack_weights<<<288, 256, 0, stream>>>(Wq, Wk, Wv, Wn, Wo, pk1, pk2, pk3);
    qkv_mfma<<<(NATOM + 127) / 128, 256, 0, stream>>>(
        atom_fea, pk1, bq, bk, bv, qbuf, kbuf, vbuf);
    attn_mfma<<<NATOM / 8, 256, 0, stream>>>(
        nbr_fea, nbr_idx, pk2, bn, qbuf, kbuf, vbuf);
    out_mfma<<<(NATOM + 63) / 64, 256, 0, stream>>>(
        qbuf, atom_fea, pk3, bo, Wg, bg, gm, bt, outp);
}

// Round 3
// 598.200 us; speedup vs baseline: 1.1345x; 1.1345x over previous
//
#include <hip/hip_runtime.h>
#include <math.h>

#define NATOM 100000
#define MNBR 12
#define FDIM 128
#define NFDIM 64

typedef __attribute__((ext_vector_type(8))) short bf16x8;
typedef __attribute__((ext_vector_type(4))) float f32x4;
typedef unsigned short u16;

__device__ inline u16 f2bf(float x) {
    union { float f; unsigned u; } v; v.f = x;
    unsigned r = v.u + 0x7FFFu + ((v.u >> 16) & 1u);   // RNE
    return (u16)(r >> 16);
}

__device__ inline float b2f(u16 u) {
    union { unsigned u; float f; } v; v.u = ((unsigned)u) << 16;
    return v.f;
}

__device__ inline float bflo(unsigned w) {
    union { unsigned u; float f; } v; v.u = w << 16; return v.f;
}
__device__ inline float bfhi(unsigned w) {
    union { unsigned u; float f; } v; v.u = w & 0xffff0000u; return v.f;
}

__device__ inline void st4bf(short* p, float4 x) {
    unsigned lo = (unsigned)f2bf(x.x) | ((unsigned)f2bf(x.y) << 16);
    unsigned hi = (unsigned)f2bf(x.z) | ((unsigned)f2bf(x.w) << 16);
    *(uint2*)p = make_uint2(lo, hi);
}

// ---------------------------------------------------------------------------
// K0: pack Wq|Wk|Wv -> pk1, Wn -> pk2, Wo -> pk3 in bf16 B-fragment order.
// pk2 uses COLUMN-PAIR tiling: frag ct covers actual cols
// (ct>>1)*32 + 2*j + (ct&1), j=0..15 — so attn's acc0/acc1 hold the
// even/odd columns of the wave's 32-col slice (matches dword gathers).
// ---------------------------------------------------------------------------
__global__ __launch_bounds__(256) void pack_weights(
    const float* __restrict__ Wq, const float* __restrict__ Wk,
    const float* __restrict__ Wv, const float* __restrict__ Wn,
    const float* __restrict__ Wo,
    short* __restrict__ pk1, short* __restrict__ pk2, short* __restrict__ pk3)
{
    int g = blockIdx.x * 256 + threadIdx.x;
    if (g < 49152) {                       // Wq|Wk|Wv: 24 frags x 4 ksteps
        int fe = g >> 9;
        int r = g & 511;
        int lane = r >> 3, jj = r & 7;
        int s = fe & 3, f = fe >> 2;
        int ct = f & 7, mt = f >> 3;
        int k = s * 32 + (lane >> 4) * 8 + jj;
        int n = ct * 16 + (lane & 15);
        const float* W = (mt == 0) ? Wq : ((mt == 1) ? Wk : Wv);
        pk1[g] = (short)f2bf(W[k * 128 + n]);
    } else if (g < 57344) {                // Wn: 8 frags x 2 ksteps (col-pair)
        int g2 = g - 49152;
        int fe = g2 >> 9;
        int r = g2 & 511;
        int lane = r >> 3, jj = r & 7;
        int s = fe & 1, ct = fe >> 1;
        int k = s * 32 + (lane >> 4) * 8 + jj;
        int n = (ct >> 1) * 32 + ((lane & 15) << 1) + (ct & 1);
        pk2[g2] = (short)f2bf(Wn[k * 128 + n]);
    } else {                               // Wo: 8 frags x 4 ksteps
        int g3 = g - 57344;
        int fe = g3 >> 9;
        int r = g3 & 511;
        int lane = r >> 3, jj = r & 7;
        int s = fe & 3, ct = fe >> 2;
        int k = s * 32 + (lane >> 4) * 8 + jj;
        int n = ct * 16 + (lane & 15);
        pk3[g3] = (short)f2bf(Wo[k * 128 + n]);
    }
}

// ---------------------------------------------------------------------------
// K1: QKV via MFMA. B-fragments hoisted to registers (loop-invariant over
// row-tiles): 24 frags = 96 VGPR, removes 168 redundant VMEM loads/wave.
// ---------------------------------------------------------------------------
__global__ __launch_bounds__(256) void qkv_mfma(
    const float* __restrict__ atom_fea,
    const short* __restrict__ pk1,
    const float* __restrict__ bq, const float* __restrict__ bk,
    const float* __restrict__ bv,
    u16* __restrict__ q, u16* __restrict__ k, u16* __restrict__ v)
{
    __shared__ short s_a[128 * 136];   // 34816 B
    const int tid = threadIdx.x;
    const int base = blockIdx.x * 128;
#pragma unroll
    for (int e = 0; e < 16; ++e) {
        int f4 = e * 256 + tid;
        int row = f4 >> 5, c4 = f4 & 31;
        int atom = base + row;
        float4 x = make_float4(0.f, 0.f, 0.f, 0.f);
        if (atom < NATOM) x = *(const float4*)(atom_fea + (size_t)atom * 128 + c4 * 4);
        st4bf(&s_a[row * 136 + c4 * 4], x);
    }

    const int lane = tid & 63, w = tid >> 6;
    const int quad = lane >> 4, j16 = lane & 15;

    bf16x8 bfr[6][4];
#pragma unroll
    for (int fl = 0; fl < 6; ++fl)
#pragma unroll
        for (int s = 0; s < 4; ++s)
            bfr[fl][s] = *(const bf16x8*)(pk1 + ((((w * 6 + fl) * 4 + s) * 64 + lane) << 3));

    __syncthreads();

    for (int rt = 0; rt < 8; ++rt) {
        f32x4 acc[6];
#pragma unroll
        for (int fl = 0; fl < 6; ++fl) acc[fl] = (f32x4){0.f, 0.f, 0.f, 0.f};

        const short* arow = &s_a[(rt * 16 + j16) * 136];
#pragma unroll
        for (int s = 0; s < 4; ++s) {
            bf16x8 af = *(const bf16x8*)(arow + s * 32 + quad * 8);
#pragma unroll
            for (int fl = 0; fl < 6; ++fl)
                acc[fl] = __builtin_amdgcn_mfma_f32_16x16x32_bf16(af, bfr[fl][s], acc[fl], 0, 0, 0);
        }
#pragma unroll
        for (int fl = 0; fl < 6; ++fl) {
            const int f = w * 6 + fl;
            const int mt = f >> 3, ct = f & 7;
            const int col = ct * 16 + j16;
            const float b = (mt == 0 ? bq : (mt == 1 ? bk : bv))[col];
            u16* op = (mt == 0 ? q : (mt == 1 ? k : v));
#pragma unroll
            for (int r = 0; r < 4; ++r) {
                int atom = base + rt * 16 + quad * 4 + r;
                if (atom < NATOM) op[(unsigned)atom * 128u + col] = f2bf(acc[fl][r] + b);
            }
        }
    }
}

// ---------------------------------------------------------------------------
// K2: fused neighbor projection (MFMA) + gather + attention.
// r1 barrier-free structure + COLUMN-PAIR layout: each lane owns cols
// {w*32+2*j16, +1}. One dword gather per (neighbor, k/v) = 6 gathers/atom
// (was 12 shorts). Head A lives in lanes 0..7, head B in 8..15 of each
// 16-lane group -> score reduce is 3 shuffles (both heads at once).
// Neighbor offsets preloaded for all 8 atoms (no dependent chain in loop).
// ---------------------------------------------------------------------------
__global__ __launch_bounds__(256) void attn_mfma(
    const float* __restrict__ nbr_fea,
    const int*   __restrict__ nbr_idx,
    const short* __restrict__ pk2,
    const float* __restrict__ bn,
    u16* qatt,
    const u16* __restrict__ kbuf,
    const u16* __restrict__ vbuf)
{
    __shared__ __align__(16) short s_a[8 * 16 * 72];   // 18432 B
    __shared__ __align__(16) u16   s_q[8 * 128];       //  2048 B
    const int tid = threadIdx.x;
    const long long blk = blockIdx.x;

    const float* gsrc = nbr_fea + blk * 6144;
#pragma unroll
    for (int e = 0; e < 6; ++e) {
        int f4 = e * 256 + tid;            // [0,1536): 96 rows x 16 float4
        int r = f4 >> 4, c4 = f4 & 15;
        int a = r / 12, m = r - a * 12;
        int lrow = (m / 3) * 4 + (m % 3);  // balanced pad layout
        float4 x = *(const float4*)(gsrc + (size_t)f4 * 4);
        st4bf(&s_a[(a * 16 + lrow) * 72 + c4 * 4], x);
    }
    {   // zero pad rows r=3 of each quad
        int prow = tid >> 3, c = tid & 7;
        int a = prow >> 2, qd = prow & 3;
        *(uint4*)&s_a[(a * 16 + qd * 4 + 3) * 72 + c * 8] = make_uint4(0, 0, 0, 0);
    }
    if (tid < 128) {                       // stage q rows for this block
        ((uint4*)s_q)[tid] = ((const uint4*)(qatt + (size_t)blk * 1024))[tid];
    }

    const int lane = tid & 63, w = tid >> 6;
    const int quad = lane >> 4, j16 = lane & 15;
    const unsigned base8 = (unsigned)blk * 8u;

    // preload all neighbor dword-offsets (quad's 3 neighbors x 8 atoms)
    unsigned voff[8][3];
#pragma unroll
    for (int a = 0; a < 8; ++a)
#pragma unroll
        for (int r = 0; r < 3; ++r)
            voff[a][r] = ((unsigned)nbr_idx[(base8 + a) * 12u + quad * 3 + r]) * 64u
                         + (unsigned)(w * 16 + j16);

    __syncthreads();

    bf16x8 bfr[2][2];                      // [hh][kstep]
#pragma unroll
    for (int hh = 0; hh < 2; ++hh)
#pragma unroll
        for (int s = 0; s < 2; ++s) {
            int ct = w * 2 + hh;
            bfr[hh][s] = *(const bf16x8*)(pk2 + (((ct * 2 + s) * 64 + lane) << 3));
        }

    const float2 bnc = *(const float2*)(bn + w * 32 + 2 * j16);
    const unsigned* kptr = (const unsigned*)kbuf;
    const unsigned* vptr = (const unsigned*)vbuf;

#pragma unroll
    for (int a = 0; a < 8; ++a) {
        // 6 dword gathers (k/v, 3 neighbors) — independent, issued up front
        unsigned kw[3], vw[3];
#pragma unroll
        for (int r = 0; r < 3; ++r) {
            kw[r] = kptr[voff[a][r]];
            vw[r] = vptr[voff[a][r]];
        }

        // neighbor projection MFMA: acc0 = even cols, acc1 = odd cols
        f32x4 acc0 = (f32x4){0.f, 0.f, 0.f, 0.f};
        f32x4 acc1 = (f32x4){0.f, 0.f, 0.f, 0.f};
#pragma unroll
        for (int s = 0; s < 2; ++s) {
            bf16x8 af = *(const bf16x8*)&s_a[(a * 16 + j16) * 72 + s * 32 + quad * 8];
            acc0 = __builtin_amdgcn_mfma_f32_16x16x32_bf16(af, bfr[0][s], acc0, 0, 0, 0);
            acc1 = __builtin_amdgcn_mfma_f32_16x16x32_bf16(af, bfr[1][s], acc1, 0, 0, 0);
        }

        unsigned qw = *(const unsigned*)&s_q[a * 128 + w * 32 + 2 * j16];
        const float q0 = bflo(qw), q1 = bfhi(qw);

        float sc[3], nv0[3], nv1[3];
#pragma unroll
        for (int r = 0; r < 3; ++r) {
            float tm0 = acc0[r] + bnc.x;               // nbr_t + bn (even col)
            float tm1 = acc1[r] + bnc.y;               // (odd col)
            float k0 = bflo(kw[r]) + tm0;
            float k1 = bfhi(kw[r]) + tm1;
            nv0[r] = bflo(vw[r]) + tm0;
            nv1[r] = bfhi(vw[r]) + tm1;
            float p = q0 * k0 + q1 * k1;
            p += __shfl_xor(p, 1, 16);
            p += __shfl_xor(p, 2, 16);
            p += __shfl_xor(p, 4, 16);                 // 8-lane half = one head
            sc[r] = p * 0.25f;                         // 1/sqrt(16)
        }
        float mx = fmaxf(fmaxf(sc[0], sc[1]), sc[2]);
        mx = fmaxf(mx, __shfl_xor(mx, 16));
        mx = fmaxf(mx, __shfl_xor(mx, 32));
        float es = 0.f, av0 = 0.f, av1 = 0.f;
#pragma unroll
        for (int r = 0; r < 3; ++r) {
            float e = __expf(sc[r] - mx);
            es += e;
            av0 += e * nv0[r];
            av1 += e * nv1[r];
        }
        es  += __shfl_xor(es, 16);  es  += __shfl_xor(es, 32);
        av0 += __shfl_xor(av0, 16); av0 += __shfl_xor(av0, 32);
        av1 += __shfl_xor(av1, 16); av1 += __shfl_xor(av1, 32);
        if (quad == 0) {
            float rs = __builtin_amdgcn_rcpf(es);
            unsigned pr = (unsigned)f2bf(av0 * rs)
                        | ((unsigned)f2bf(av1 * rs) << 16);
            *(unsigned*)&qatt[(base8 + a) * 128u + w * 32 + 2 * j16] = pr;
        }
    }
}

// ---------------------------------------------------------------------------
// K3: out projection (MFMA) + sigmoid gate + residual + LayerNorm (unchanged).
// ---------------------------------------------------------------------------
__global__ __launch_bounds__(256) void out_mfma(
    const u16* __restrict__ attb, const float* __restrict__ atom_fea,
    const short* __restrict__ pk3, const float* __restrict__ bo,
    const float* __restrict__ Wg, const float* __restrict__ bg,
    const float* __restrict__ gamma, const float* __restrict__ beta,
    float* __restrict__ out)
{
    __shared__ short s_a[64 * 136];    // 17408 B (att tile, bf16)
    __shared__ float s_o[64 * 132];    // 33792 B (out tile, fp32)
    const int tid = threadIdx.x;
    const int base = blockIdx.x * 64;
#pragma unroll
    for (int e = 0; e < 4; ++e) {
        int u = e * 256 + tid;             // 64 rows x 16 uint4
        int row = u >> 4, c8 = u & 15;
        int atom = base + row;
        uint4 x = make_uint4(0, 0, 0, 0);
        if (atom < NATOM) x = *(const uint4*)(attb + (size_t)atom * 128 + c8 * 8);
        *(uint4*)&s_a[row * 136 + c8 * 8] = x;
    }
    __syncthreads();

    const int lane = tid & 63, w = tid >> 6;
    const int quad = lane >> 4, j16 = lane & 15;

    f32x4 acc[8];
#pragma unroll
    for (int f = 0; f < 8; ++f) acc[f] = (f32x4){0.f, 0.f, 0.f, 0.f};

    const short* arow = &s_a[(w * 16 + j16) * 136];
#pragma unroll
    for (int s = 0; s < 4; ++s) {
        bf16x8 af = *(const bf16x8*)(arow + s * 32 + quad * 8);
        bf16x8 bfr[8];
#pragma unroll
        for (int f = 0; f < 8; ++f)
            bfr[f] = *(const bf16x8*)(pk3 + (((f * 4 + s) * 64 + lane) << 3));
#pragma unroll
        for (int f = 0; f < 8; ++f)
            acc[f] = __builtin_amdgcn_mfma_f32_16x16x32_bf16(af, bfr[f], acc[f], 0, 0, 0);
    }
#pragma unroll
    for (int f = 0; f < 8; ++f) {
        const int col = f * 16 + j16;
        const float b = bo[col];
#pragma unroll
        for (int r = 0; r < 4; ++r)
            s_o[(w * 16 + quad * 4 + r) * 132 + col] = acc[f][r] + b;
    }
    __syncthreads();

    const int g = tid >> 4;
    const int r16 = tid & 15;
    for (int p = 0; p < 4; ++p) {
        const int a_loc = p * 16 + g;
        const int atom = base + a_loc;
        const bool ok = (atom < NATOM);
        float o8[8], res8[8];
        float pg = 0.f;
#pragma unroll
        for (int tt = 0; tt < 8; ++tt) {
            int jj = r16 + tt * 16;
            o8[tt] = s_o[a_loc * 132 + jj];
            res8[tt] = ok ? atom_fea[(size_t)atom * 128 + jj] : 0.f;
            pg += o8[tt] * Wg[jj] + res8[tt] * Wg[128 + jj];
        }
        pg += __shfl_xor(pg, 1, 16);
        pg += __shfl_xor(pg, 2, 16);
        pg += __shfl_xor(pg, 4, 16);
        pg += __shfl_xor(pg, 8, 16);
        const float gt = 1.f / (1.f + __expf(-(pg + bg[0])));

        float s1 = 0.f, s2 = 0.f;
        float gv8[8];
#pragma unroll
        for (int tt = 0; tt < 8; ++tt) {
            float gv = gt * o8[tt] + (1.f - gt) * res8[tt];
            gv8[tt] = gv;
            s1 += gv; s2 += gv * gv;
        }
        s1 += __shfl_xor(s1, 1, 16); s2 += __shfl_xor(s2, 1, 16);
        s1 += __shfl_xor(s1, 2, 16); s2 += __shfl_xor(s2, 2, 16);
        s1 += __shfl_xor(s1, 4, 16); s2 += __shfl_xor(s2, 4, 16);
        s1 += __shfl_xor(s1, 8, 16); s2 += __shfl_xor(s2, 8, 16);
        const float mu = s1 * (1.f / 128.f);
        const float var = s2 * (1.f / 128.f) - mu * mu;
        const float rs = rsqrtf(var + 1e-5f);
        if (ok) {
#pragma unroll
            for (int tt = 0; tt < 8; ++tt) {
                int jj = r16 + tt * 16;
                out[(size_t)atom * 128 + jj] =
                    (gv8[tt] - mu) * rs * gamma[jj] + beta[jj];
            }
        }
    }
}

// ---------------------------------------------------------------------------
extern "C" void kernel_launch(void* const* d_in, const int* in_sizes, int n_in,
                              void* d_out, int out_size, void* d_ws, size_t ws_size,
                              hipStream_t stream) {
    const float* atom_fea = (const float*)d_in[0];
    const float* nbr_fea  = (const float*)d_in[1];
    const int*   nbr_idx  = (const int*)d_in[2];
    const float* Wq = (const float*)d_in[3];
    const float* bq = (const float*)d_in[4];
    const float* Wk = (const float*)d_in[5];
    const float* bk = (const float*)d_in[6];
    const float* Wv = (const float*)d_in[7];
    const float* bv = (const float*)d_in[8];
    const float* Wn = (const float*)d_in[9];
    const float* bn = (const float*)d_in[10];
    const float* Wo = (const float*)d_in[11];
    const float* bo = (const float*)d_in[12];
    const float* Wg = (const float*)d_in[13];
    const float* bg = (const float*)d_in[14];
    const float* gm = (const float*)d_in[15];
    const float* bt = (const float*)d_in[16];

    u16* qbuf = (u16*)d_ws;                           // [N,128] bf16 -> att
    u16* kbuf = qbuf + (size_t)NATOM * FDIM;
    u16* vbuf = kbuf + (size_t)NATOM * FDIM;
    short* pk1 = (short*)(vbuf + (size_t)NATOM * FDIM);   // 49152 bf16
    short* pk2 = pk1 + 49152;                             // 8192 bf16
    short* pk3 = pk2 + 8192;                              // 16384 bf16
    float* outp = (float*)d_out;

    pack_weights<<<288, 256, 0, stream>>>(Wq, Wk, Wv, Wn, Wo, pk1, pk2, pk3);
    qkv_mfma<<<(NATOM + 127) / 128, 256, 0, stream>>>(
        atom_fea, pk1, bq, bk, bv, qbuf, kbuf, vbuf);
    attn_mfma<<<NATOM / 8, 256, 0, stream>>>(
        nbr_fea, nbr_idx, pk2, bn, qbuf, kbuf, vbuf);
    out_mfma<<<(NATOM + 63) / 64, 256, 0, stream>>>(
        qbuf, atom_fea, pk3, bo, Wg, bg, gm, bt, outp);
}